// Round 2
// baseline (751.270 us; speedup 1.0000x reference)
//
#include <hip/hip_runtime.h>

#define N_NODE 80000
#define N_NET  20000
#define NE     150000
#define GROW   544   // 16 k-rows * 32 outputs + 32-wide bias row

typedef unsigned short u16;
typedef unsigned int u32;
typedef __attribute__((ext_vector_type(8))) short short8v;
typedef __attribute__((ext_vector_type(4))) float f32x4;

static __device__ __forceinline__ u16 f2bf(float f) {
  u32 x = __float_as_uint(f);
  x += 0x7fffu + ((x >> 16) & 1u);   // round-to-nearest-even
  return (u16)(x >> 16);
}
static __device__ __forceinline__ float bflo(u32 u) { return __uint_as_float(u << 16); }
static __device__ __forceinline__ float bfhi(u32 u) { return __uint_as_float(u & 0xffff0000u); }

// Build TRANSPOSED B matrices BT[544][32] bf16:
//   BT[n][i] = W[(i*32 + (n&31))*16 + (n>>5)]  for n < 512
//   BT[512+o][i] = b[i*32+o]                   (bias row, coefficient 1)
__global__ __launch_bounds__(256) void bmat_kernel(
    const float* __restrict__ topo_w, const float* __restrict__ topo_b,
    const float* __restrict__ geom_w, const float* __restrict__ geom_b,
    u16* __restrict__ BTt, u16* __restrict__ BTg) {
  int idx = blockIdx.x * 256 + threadIdx.x;          // 2 * 544 * 32 = 34816 exact
  int which = idx / (GROW * 32);
  int r = idx % (GROW * 32);
  int n = r >> 5, i = r & 31;
  int k = n >> 5, o = n & 31;
  const float* w = which ? geom_w : topo_w;
  const float* b = which ? geom_b : topo_b;
  float v = (k < 16) ? w[(i * 32 + o) * 16 + k] : b[i * 32 + o];
  (which ? BTg : BTt)[n * 32 + i] = f2bf(v);
}

// G[s][n] = sum_i feat[s][i] * B[i][n], via mfma(A=BT-slice, B=feat^T):
// D col (lane&15) = source row, D rows (4*(lane>>4)+r4) = 4 consecutive G cols
// -> each lane stores one dwordx2 (4 bf16) per MFMA, per-row-contiguous.
__global__ __launch_bounds__(256) void g_precompute(
    const float* __restrict__ feat, const u16* __restrict__ BT,
    u16* __restrict__ G, int nrows) {
  int wave = (blockIdx.x * 256 + threadIdx.x) >> 6;
  int lane = threadIdx.x & 63;
  int s0 = wave * 16;
  if (s0 >= nrows) return;
  int c  = lane & 15;           // source row within tile / D column
  int kg = lane >> 4;
  int k0 = kg * 8;              // 8 consecutive K elements per lane

  const float* ap = feat + (size_t)(s0 + c) * 32 + k0;
  float4 a0 = *(const float4*)ap;
  float4 a1 = *(const float4*)(ap + 4);
  short8v ff;
  ff[0]=(short)f2bf(a0.x); ff[1]=(short)f2bf(a0.y); ff[2]=(short)f2bf(a0.z); ff[3]=(short)f2bf(a0.w);
  ff[4]=(short)f2bf(a1.x); ff[5]=(short)f2bf(a1.y); ff[6]=(short)f2bf(a1.z); ff[7]=(short)f2bf(a1.w);

  u16* gp = G + (size_t)(s0 + c) * GROW + kg * 4;
#pragma unroll 2
  for (int t = 0; t < 34; ++t) {
    // A-frag: rows = G-cols t*16+c, 8 consecutive k -> contiguous 16B in BT
    short8v at = *(const short8v*)(BT + (size_t)(t * 16 + c) * 32 + k0);
    f32x4 cc = {0.f, 0.f, 0.f, 0.f};
    cc = __builtin_amdgcn_mfma_f32_16x16x32_bf16(at, ff, cc, 0, 0, 0);
    u32 u0 = (u32)f2bf(cc[0]) | ((u32)f2bf(cc[1]) << 16);
    u32 u1 = (u32)f2bf(cc[2]) | ((u32)f2bf(cc[3]) << 16);
    *(uint2*)(gp + t * 16) = make_uint2(u0, u1);
  }
}

__global__ __launch_bounds__(256) void deg_kernel(
    const int* __restrict__ pins_src, const int* __restrict__ pins_dst,
    const int* __restrict__ pinned_dst, const int* __restrict__ near_dst,
    float* __restrict__ deg_out, float* __restrict__ deg_in,
    float* __restrict__ deg_p, float* __restrict__ deg_n) {
  int e = blockIdx.x * 256 + threadIdx.x;
  if (e >= NE) return;
  atomicAdd(deg_out + pins_src[e], 1.0f);
  atomicAdd(deg_in  + pins_dst[e], 1.0f);
  atomicAdd(deg_p   + pinned_dst[e], 1.0f);
  atomicAdd(deg_n   + near_dst[e], 1.0f);
}

// GraphConv message: agg[dst] += node_feat[src] * rsqrt(max(deg_out[src],1))
__global__ __launch_bounds__(256) void pins_edge_kernel(
    const float* __restrict__ node_feat, const int* __restrict__ src,
    const int* __restrict__ dst, const float* __restrict__ deg_out,
    float* __restrict__ agg) {
  int gid = blockIdx.x * 256 + threadIdx.x;
  int e = gid >> 5;
  if (e >= NE) return;
  int o = gid & 31;
  int s = src[e], d = dst[e];
  float ns = rsqrtf(fmaxf(deg_out[s], 1.0f));
  atomicAdd(agg + (size_t)d * 32 + o, node_feat[(size_t)s * 32 + o] * ns);
}

// NNConv message, one THREAD per edge: full 1088B G-row via 68 dwordx4 loads.
// msg[o] = G[s][512+o] + sum_k ef[e][k]*G[s][k*32+o].  Both relations fused.
__global__ __launch_bounds__(256) void nnconv_edge_kernel(
    const u16* __restrict__ G0, const float* __restrict__ ef0,
    const int* __restrict__ src0, const int* __restrict__ dst0, float* __restrict__ acc0,
    const u16* __restrict__ G1, const float* __restrict__ ef1,
    const int* __restrict__ src1, const int* __restrict__ dst1, float* __restrict__ acc1,
    int nb0) {
  int b = blockIdx.x;
  bool rel = (b >= nb0);
  int e = (rel ? b - nb0 : b) * 256 + threadIdx.x;
  if (e >= NE) return;
  const u16* G      = rel ? G1 : G0;
  const float* ef   = rel ? ef1 : ef0;
  const int* srcp   = rel ? src1 : src0;
  const int* dstp   = rel ? dst1 : dst0;
  float* acc        = rel ? acc1 : acc0;

  int s = srcp[e], d = dstp[e];
  const uint4* g = (const uint4*)(G + (size_t)s * GROW);
  const float4* pfp = (const float4*)(ef + (size_t)e * 16);
  float4 p0 = pfp[0], p1 = pfp[1], p2 = pfp[2], p3 = pfp[3];
  float pv[16] = {p0.x,p0.y,p0.z,p0.w, p1.x,p1.y,p1.z,p1.w,
                  p2.x,p2.y,p2.z,p2.w, p3.x,p3.y,p3.z,p3.w};
  float m[32];
#pragma unroll
  for (int c = 64; c < 68; ++c) {     // bias chunks: n = 512 + (c&3)*8 + j
    uint4 w = g[c];
    int o0 = (c & 3) * 8;
    m[o0+0] = bflo(w.x); m[o0+1] = bfhi(w.x);
    m[o0+2] = bflo(w.y); m[o0+3] = bfhi(w.y);
    m[o0+4] = bflo(w.z); m[o0+5] = bfhi(w.z);
    m[o0+6] = bflo(w.w); m[o0+7] = bfhi(w.w);
  }
#pragma unroll
  for (int c = 0; c < 64; ++c) {      // chunk c: k = c>>2, o = (c&3)*8 + j
    uint4 w = g[c];
    float pk = pv[c >> 2];
    int o0 = (c & 3) * 8;
    m[o0+0] += pk * bflo(w.x); m[o0+1] += pk * bfhi(w.x);
    m[o0+2] += pk * bflo(w.y); m[o0+3] += pk * bfhi(w.y);
    m[o0+4] += pk * bflo(w.z); m[o0+5] += pk * bfhi(w.z);
    m[o0+6] += pk * bflo(w.w); m[o0+7] += pk * bfhi(w.w);
  }
  float* ap = acc + (size_t)d * 32;
#pragma unroll
  for (int o = 0; o < 32; ++o) atomicAdd(ap + o, m[o]);
}

// net_out = rsqrt(max(deg_in,1)) * (agg @ gc_w) + gc_b
__global__ __launch_bounds__(256) void net_out_kernel(
    const float* __restrict__ agg, const float* __restrict__ deg_in,
    const float* __restrict__ gc_w, const float* __restrict__ gc_b,
    float* __restrict__ out) {
  int gid = blockIdx.x * 256 + threadIdx.x;
  int m = gid >> 5;
  if (m >= N_NET) return;
  int o = gid & 31;
  float nd = rsqrtf(fmaxf(deg_in[m], 1.0f));
  const float* ag = agg + (size_t)m * 32;
  float a = 0.f;
#pragma unroll
  for (int j = 0; j < 32; ++j) a += ag[j] * gc_w[j * 32 + o];
  out[(size_t)N_NODE * 32 + (size_t)m * 32 + o] = a * nd + gc_b[o];
}

// node_out = max(acc_p/deg_p + pinned_b, acc_n/deg_n + near_b)
__global__ __launch_bounds__(256) void node_out_kernel(
    const float* __restrict__ acc_p, const float* __restrict__ acc_n,
    const float* __restrict__ deg_p, const float* __restrict__ deg_n,
    const float* __restrict__ pinned_b, const float* __restrict__ near_b,
    float* __restrict__ out) {
  int gid = blockIdx.x * 256 + threadIdx.x;
  int v = gid >> 5;
  if (v >= N_NODE) return;
  int o = gid & 31;
  float ap = acc_p[gid] / fmaxf(deg_p[v], 1.0f) + pinned_b[o];
  float an = acc_n[gid] / fmaxf(deg_n[v], 1.0f) + near_b[o];
  out[gid] = fmaxf(ap, an);
}

extern "C" void kernel_launch(void* const* d_in, const int* in_sizes, int n_in,
                              void* d_out, int out_size, void* d_ws, size_t ws_size,
                              hipStream_t stream) {
  const float* node_feat = (const float*)d_in[0];
  const float* net_feat  = (const float*)d_in[1];
  const float* pin_feat  = (const float*)d_in[2];
  const float* edge_feat = (const float*)d_in[3];
  const float* topo_w    = (const float*)d_in[4];
  const float* topo_b    = (const float*)d_in[5];
  const float* geom_w    = (const float*)d_in[6];
  const float* geom_b    = (const float*)d_in[7];
  const float* gc_w      = (const float*)d_in[8];
  const float* gc_b      = (const float*)d_in[9];
  const float* pinned_b  = (const float*)d_in[10];
  const float* near_b    = (const float*)d_in[11];
  const int* pins_src    = (const int*)d_in[12];
  const int* pins_dst    = (const int*)d_in[13];
  const int* pinned_src  = (const int*)d_in[14];
  const int* pinned_dst  = (const int*)d_in[15];
  const int* near_src    = (const int*)d_in[16];
  const int* near_dst    = (const int*)d_in[17];

  char* ws = (char*)d_ws;
  float* acc_p   = (float*)ws;            // 2,560,000 f32
  float* acc_n   = acc_p + 2560000;       // 2,560,000
  float* agg     = acc_n + 2560000;       //   640,000
  float* deg_out = agg + 640000;          //    80,000
  float* deg_in  = deg_out + 80000;       //    20,000
  float* deg_p   = deg_in + 20000;        //    80,000
  float* deg_n   = deg_p + 80000;         //    80,000
  size_t zero_bytes = (size_t)6020000 * 4;
  size_t off = (zero_bytes + 255) & ~(size_t)255;
  u16* G_net  = (u16*)(ws + off);  off += (size_t)N_NET * GROW * 2;
  off = (off + 255) & ~(size_t)255;
  u16* G_node = (u16*)(ws + off);  off += (size_t)N_NODE * GROW * 2;
  off = (off + 255) & ~(size_t)255;
  u16* BTt = (u16*)(ws + off);     off += (size_t)GROW * 32 * 2;
  u16* BTg = (u16*)(ws + off);

  hipMemsetAsync(d_ws, 0, zero_bytes, stream);
  bmat_kernel<<<136, 256, 0, stream>>>(topo_w, topo_b, geom_w, geom_b, BTt, BTg);
  g_precompute<<<313, 256, 0, stream>>>(net_feat, BTt, G_net, N_NET);      // 1250 waves
  g_precompute<<<1250, 256, 0, stream>>>(node_feat, BTg, G_node, N_NODE);  // 5000 waves
  deg_kernel<<<(NE + 255) / 256, 256, 0, stream>>>(pins_src, pins_dst, pinned_dst, near_dst,
                                                   deg_out, deg_in, deg_p, deg_n);
  pins_edge_kernel<<<NE * 32 / 256, 256, 0, stream>>>(node_feat, pins_src, pins_dst, deg_out, agg);
  int nb0 = (NE + 255) / 256;  // 586
  nnconv_edge_kernel<<<2 * nb0, 256, 0, stream>>>(
      G_net, pin_feat, pinned_src, pinned_dst, acc_p,
      G_node, edge_feat, near_src, near_dst, acc_n, nb0);
  net_out_kernel<<<N_NET * 32 / 256, 256, 0, stream>>>(agg, deg_in, gc_w, gc_b, (float*)d_out);
  node_out_kernel<<<N_NODE * 32 / 256, 256, 0, stream>>>(acc_p, acc_n, deg_p, deg_n,
                                                         pinned_b, near_b, (float*)d_out);
}

// Round 3
// 284.606 us; speedup vs baseline: 2.6397x; 2.6397x over previous
//
#include <hip/hip_runtime.h>

#define N_NODE 80000
#define N_NET  20000
#define NE     150000
#define GROW   544   // 16 k-rows * 32 outputs + 32-wide bias row (k-major: n = k*32+o)

typedef unsigned short u16;
typedef unsigned int u32;
typedef __attribute__((ext_vector_type(8))) short short8v;
typedef __attribute__((ext_vector_type(4))) float f32x4;

static __device__ __forceinline__ u16 f2bf(float f) {
  u32 x = __float_as_uint(f);
  x += 0x7fffu + ((x >> 16) & 1u);   // round-to-nearest-even
  return (u16)(x >> 16);
}
static __device__ __forceinline__ float bflo(u32 u) { return __uint_as_float(u << 16); }
static __device__ __forceinline__ float bfhi(u32 u) { return __uint_as_float(u & 0xffff0000u); }

// Build TRANSPOSED B matrices BT[544][32] bf16:
//   BT[n][i] = W[(i*32 + (n&31))*16 + (n>>5)]  for n < 512
//   BT[512+o][i] = b[i*32+o]                   (bias row, coefficient 1)
__global__ __launch_bounds__(256) void bmat_kernel(
    const float* __restrict__ topo_w, const float* __restrict__ topo_b,
    const float* __restrict__ geom_w, const float* __restrict__ geom_b,
    u16* __restrict__ BTt, u16* __restrict__ BTg) {
  int idx = blockIdx.x * 256 + threadIdx.x;          // 2 * 544 * 32 = 34816 exact
  int which = idx / (GROW * 32);
  int r = idx % (GROW * 32);
  int n = r >> 5, i = r & 31;
  int k = n >> 5, o = n & 31;
  const float* w = which ? geom_w : topo_w;
  const float* b = which ? geom_b : topo_b;
  float v = (k < 16) ? w[(i * 32 + o) * 16 + k] : b[i * 32 + o];
  (which ? BTg : BTt)[n * 32 + i] = f2bf(v);
}

// G[s][n] = sum_i feat[s][i] * B[i][n], via mfma(A=BT-slice, B=feat^T):
// D col (lane&15) = source row, D rows (4*(lane>>4)+r4) = 4 consecutive G cols
// -> each lane stores one dwordx2 (4 bf16) per MFMA, per-row-contiguous.
__global__ __launch_bounds__(256) void g_precompute(
    const float* __restrict__ feat, const u16* __restrict__ BT,
    u16* __restrict__ G, int nrows) {
  int wave = (blockIdx.x * 256 + threadIdx.x) >> 6;
  int lane = threadIdx.x & 63;
  int s0 = wave * 16;
  if (s0 >= nrows) return;
  int c  = lane & 15;           // source row within tile / D column
  int kg = lane >> 4;
  int k0 = kg * 8;              // 8 consecutive K elements per lane

  const float* ap = feat + (size_t)(s0 + c) * 32 + k0;
  float4 a0 = *(const float4*)ap;
  float4 a1 = *(const float4*)(ap + 4);
  short8v ff;
  ff[0]=(short)f2bf(a0.x); ff[1]=(short)f2bf(a0.y); ff[2]=(short)f2bf(a0.z); ff[3]=(short)f2bf(a0.w);
  ff[4]=(short)f2bf(a1.x); ff[5]=(short)f2bf(a1.y); ff[6]=(short)f2bf(a1.z); ff[7]=(short)f2bf(a1.w);

  u16* gp = G + (size_t)(s0 + c) * GROW + kg * 4;
#pragma unroll 2
  for (int t = 0; t < 34; ++t) {
    // A-frag: rows = G-cols t*16+c, 8 consecutive k -> contiguous 16B in BT
    short8v at = *(const short8v*)(BT + (size_t)(t * 16 + c) * 32 + k0);
    f32x4 cc = {0.f, 0.f, 0.f, 0.f};
    cc = __builtin_amdgcn_mfma_f32_16x16x32_bf16(at, ff, cc, 0, 0, 0);
    u32 u0 = (u32)f2bf(cc[0]) | ((u32)f2bf(cc[1]) << 16);
    u32 u1 = (u32)f2bf(cc[2]) | ((u32)f2bf(cc[3]) << 16);
    *(uint2*)(gp + t * 16) = make_uint2(u0, u1);
  }
}

__global__ __launch_bounds__(256) void deg_kernel(
    const int* __restrict__ pins_src, const int* __restrict__ pins_dst,
    const int* __restrict__ pinned_dst, const int* __restrict__ near_dst,
    float* __restrict__ deg_out, float* __restrict__ deg_in,
    float* __restrict__ deg_p, float* __restrict__ deg_n) {
  int e = blockIdx.x * 256 + threadIdx.x;
  if (e >= NE) return;
  atomicAdd(deg_out + pins_src[e], 1.0f);
  atomicAdd(deg_in  + pins_dst[e], 1.0f);
  atomicAdd(deg_p   + pinned_dst[e], 1.0f);
  atomicAdd(deg_n   + near_dst[e], 1.0f);
}

// GraphConv message: agg[dst] += node_feat[src] * rsqrt(max(deg_out[src],1))
__global__ __launch_bounds__(256) void pins_edge_kernel(
    const float* __restrict__ node_feat, const int* __restrict__ src,
    const int* __restrict__ dst, const float* __restrict__ deg_out,
    float* __restrict__ agg) {
  int gid = blockIdx.x * 256 + threadIdx.x;
  int e = gid >> 5;
  if (e >= NE) return;
  int o = gid & 31;
  int s = src[e], d = dst[e];
  float ns = rsqrtf(fmaxf(deg_out[s], 1.0f));
  atomicAdd(agg + (size_t)d * 32 + o, node_feat[(size_t)s * 32 + o] * ns);
}

// NNConv messages. 16 edges per wave, 4 lanes per edge (lane&3 owns 8 outputs).
// Gather phase: per k one dwordx4/lane -> 17 coalesced 1KB load instrs / 16 edges.
// Then wave-local LDS transpose (stride-33 rows: only 2-way bank alias = free)
// so the atomic phase uses the proven pattern: 2 edges x 32 consecutive lanes
// per atomic instruction (L2 merges same-line atomics -> write-once traffic).
__global__ __launch_bounds__(256) void nnconv_edge_kernel(
    const u16* __restrict__ G0, const float* __restrict__ ef0,
    const int* __restrict__ src0, const int* __restrict__ dst0, float* __restrict__ acc0,
    const u16* __restrict__ G1, const float* __restrict__ ef1,
    const int* __restrict__ src1, const int* __restrict__ dst1, float* __restrict__ acc1,
    int nb0) {
  __shared__ float lds[4][16 * 33];
  int w = threadIdx.x >> 6, lane = threadIdx.x & 63;
  bool rel = (blockIdx.x >= nb0);
  int b = rel ? blockIdx.x - nb0 : blockIdx.x;
  const u16* G      = rel ? G1 : G0;
  const float* ef   = rel ? ef1 : ef0;
  const int* srcp   = rel ? src1 : src0;
  const int* dstp   = rel ? dst1 : dst0;
  float* acc        = rel ? acc1 : acc0;

  int e0 = b * 64 + w * 16;
  int eil = lane >> 2, lane4 = lane & 3;
  int e = e0 + eil;
  if (e < NE) {
    int s = srcp[e];
    const float4* pfp = (const float4*)(ef + (size_t)e * 16);
    float4 p0 = pfp[0], p1 = pfp[1], p2 = pfp[2], p3 = pfp[3];
    float pv[16] = {p0.x,p0.y,p0.z,p0.w, p1.x,p1.y,p1.z,p1.w,
                    p2.x,p2.y,p2.z,p2.w, p3.x,p3.y,p3.z,p3.w};
    const u16* g = G + (size_t)s * GROW;
    uint4 bw = *(const uint4*)(g + 512 + lane4 * 8);   // bias, 16B aligned
    float m[8];
    m[0]=bflo(bw.x); m[1]=bfhi(bw.x); m[2]=bflo(bw.y); m[3]=bfhi(bw.y);
    m[4]=bflo(bw.z); m[5]=bfhi(bw.z); m[6]=bflo(bw.w); m[7]=bfhi(bw.w);
#pragma unroll
    for (int k = 0; k < 16; ++k) {
      uint4 wv = *(const uint4*)(g + k * 32 + lane4 * 8);  // 16B aligned
      float pk = pv[k];
      m[0] += pk * bflo(wv.x); m[1] += pk * bfhi(wv.x);
      m[2] += pk * bflo(wv.y); m[3] += pk * bfhi(wv.y);
      m[4] += pk * bflo(wv.z); m[5] += pk * bfhi(wv.z);
      m[6] += pk * bflo(wv.w); m[7] += pk * bfhi(wv.w);
    }
    float* row = &lds[w][eil * 33];
#pragma unroll
    for (int j = 0; j < 8; ++j) row[lane4 * 8 + j] = m[j];
  }
  __syncthreads();
  int half = lane >> 5, o = lane & 31;
#pragma unroll
  for (int r = 0; r < 8; ++r) {
    int ee = r * 2 + half;
    int er = e0 + ee;
    if (er < NE) {
      int d = dstp[er];
      atomicAdd(acc + (size_t)d * 32 + o, lds[w][ee * 33 + o]);
    }
  }
}

// net_out = rsqrt(max(deg_in,1)) * (agg @ gc_w) + gc_b
__global__ __launch_bounds__(256) void net_out_kernel(
    const float* __restrict__ agg, const float* __restrict__ deg_in,
    const float* __restrict__ gc_w, const float* __restrict__ gc_b,
    float* __restrict__ out) {
  int gid = blockIdx.x * 256 + threadIdx.x;
  int m = gid >> 5;
  if (m >= N_NET) return;
  int o = gid & 31;
  float nd = rsqrtf(fmaxf(deg_in[m], 1.0f));
  const float* ag = agg + (size_t)m * 32;
  float a = 0.f;
#pragma unroll
  for (int j = 0; j < 32; ++j) a += ag[j] * gc_w[j * 32 + o];
  out[(size_t)N_NODE * 32 + (size_t)m * 32 + o] = a * nd + gc_b[o];
}

// node_out = max(acc_p/deg_p + pinned_b, acc_n/deg_n + near_b)
__global__ __launch_bounds__(256) void node_out_kernel(
    const float* __restrict__ acc_p, const float* __restrict__ acc_n,
    const float* __restrict__ deg_p, const float* __restrict__ deg_n,
    const float* __restrict__ pinned_b, const float* __restrict__ near_b,
    float* __restrict__ out) {
  int gid = blockIdx.x * 256 + threadIdx.x;
  int v = gid >> 5;
  if (v >= N_NODE) return;
  int o = gid & 31;
  float ap = acc_p[gid] / fmaxf(deg_p[v], 1.0f) + pinned_b[o];
  float an = acc_n[gid] / fmaxf(deg_n[v], 1.0f) + near_b[o];
  out[gid] = fmaxf(ap, an);
}

extern "C" void kernel_launch(void* const* d_in, const int* in_sizes, int n_in,
                              void* d_out, int out_size, void* d_ws, size_t ws_size,
                              hipStream_t stream) {
  const float* node_feat = (const float*)d_in[0];
  const float* net_feat  = (const float*)d_in[1];
  const float* pin_feat  = (const float*)d_in[2];
  const float* edge_feat = (const float*)d_in[3];
  const float* topo_w    = (const float*)d_in[4];
  const float* topo_b    = (const float*)d_in[5];
  const float* geom_w    = (const float*)d_in[6];
  const float* geom_b    = (const float*)d_in[7];
  const float* gc_w      = (const float*)d_in[8];
  const float* gc_b      = (const float*)d_in[9];
  const float* pinned_b  = (const float*)d_in[10];
  const float* near_b    = (const float*)d_in[11];
  const int* pins_src    = (const int*)d_in[12];
  const int* pins_dst    = (const int*)d_in[13];
  const int* pinned_src  = (const int*)d_in[14];
  const int* pinned_dst  = (const int*)d_in[15];
  const int* near_src    = (const int*)d_in[16];
  const int* near_dst    = (const int*)d_in[17];

  char* ws = (char*)d_ws;
  float* acc_p   = (float*)ws;            // 2,560,000 f32
  float* acc_n   = acc_p + 2560000;       // 2,560,000
  float* agg     = acc_n + 2560000;       //   640,000
  float* deg_out = agg + 640000;          //    80,000
  float* deg_in  = deg_out + 80000;       //    20,000
  float* deg_p   = deg_in + 20000;        //    80,000
  float* deg_n   = deg_p + 80000;         //    80,000
  size_t zero_bytes = (size_t)6020000 * 4;
  size_t off = (zero_bytes + 255) & ~(size_t)255;
  u16* G_net  = (u16*)(ws + off);  off += (size_t)N_NET * GROW * 2;
  off = (off + 255) & ~(size_t)255;
  u16* G_node = (u16*)(ws + off);  off += (size_t)N_NODE * GROW * 2;
  off = (off + 255) & ~(size_t)255;
  u16* BTt = (u16*)(ws + off);     off += (size_t)GROW * 32 * 2;
  u16* BTg = (u16*)(ws + off);

  hipMemsetAsync(d_ws, 0, zero_bytes, stream);
  bmat_kernel<<<136, 256, 0, stream>>>(topo_w, topo_b, geom_w, geom_b, BTt, BTg);
  g_precompute<<<313, 256, 0, stream>>>(net_feat, BTt, G_net, N_NET);      // 1250 waves
  g_precompute<<<1250, 256, 0, stream>>>(node_feat, BTg, G_node, N_NODE);  // 5000 waves
  deg_kernel<<<(NE + 255) / 256, 256, 0, stream>>>(pins_src, pins_dst, pinned_dst, near_dst,
                                                   deg_out, deg_in, deg_p, deg_n);
  pins_edge_kernel<<<NE * 32 / 256, 256, 0, stream>>>(node_feat, pins_src, pins_dst, deg_out, agg);
  int nb0 = (NE + 63) / 64;  // 2344 blocks per relation (64 edges per block)
  nnconv_edge_kernel<<<2 * nb0, 256, 0, stream>>>(
      G_net, pin_feat, pinned_src, pinned_dst, acc_p,
      G_node, edge_feat, near_src, near_dst, acc_n, nb0);
  net_out_kernel<<<N_NET * 32 / 256, 256, 0, stream>>>(agg, deg_in, gc_w, gc_b, (float*)d_out);
  node_out_kernel<<<N_NODE * 32 / 256, 256, 0, stream>>>(acc_p, acc_n, deg_p, deg_n,
                                                         pinned_b, near_b, (float*)d_out);
}

// Round 4
// 212.856 us; speedup vs baseline: 3.5295x; 1.3371x over previous
//
#include <hip/hip_runtime.h>

#define N_NODE 80000
#define N_NET  20000
#define NE     150000
#define WLN    17408   // 34 c2h-steps * 512 u16 (64 lanes * 8 bf16) per relation

typedef unsigned short u16;
typedef unsigned int u32;
typedef __attribute__((ext_vector_type(8))) short short8v;
typedef __attribute__((ext_vector_type(4))) float f32x4;

static __device__ __forceinline__ u16 f2bf(float f) {
  u32 x = __float_as_uint(f);
  x += 0x7fffu + ((x >> 16) & 1u);   // round-to-nearest-even
  return (u16)(x >> 16);
}

// Build W' tables in exact MFMA B-fragment lane order, per relation:
//   K-index = k*32 + i (k-major).  Step c (0..16), half h (o = 16h+o'):
//   WL[(c*2+h)*512 + lane*8 + j] = W'[(c, kg*8+j), 16h+o']   (lane = kg*16+o')
//   W'[(k,i),o] = W[(i*32+o)*16 + k] for k<16;  = b[i*32+o] for k==16 (bias).
__global__ __launch_bounds__(256) void wprep_kernel(
    const float* __restrict__ topo_w, const float* __restrict__ topo_b,
    const float* __restrict__ geom_w, const float* __restrict__ geom_b,
    u16* __restrict__ WL0, u16* __restrict__ WL1) {
  int idx = blockIdx.x * 256 + threadIdx.x;   // 2*17408 = 34816 exact
  int rel = idx / WLN;
  int g = idx % WLN;
  int c2h = g >> 9, l = (g >> 3) & 63, j = g & 7;
  int op = l & 15, kg = l >> 4, c = c2h >> 1, h = c2h & 1;
  int i = kg * 8 + j, o = 16 * h + op;
  const float* w = rel ? geom_w : topo_w;
  const float* b = rel ? geom_b : topo_b;
  float v = (c < 16) ? w[(i * 32 + o) * 16 + c] : b[i * 32 + o];
  (rel ? WL1 : WL0)[g] = f2bf(v);
}

__global__ __launch_bounds__(256) void deg_kernel(
    const int* __restrict__ pins_src, const int* __restrict__ pins_dst,
    const int* __restrict__ pinned_dst, const int* __restrict__ near_dst,
    float* __restrict__ deg_out, float* __restrict__ deg_in,
    float* __restrict__ deg_p, float* __restrict__ deg_n) {
  int e = blockIdx.x * 256 + threadIdx.x;
  if (e >= NE) return;
  atomicAdd(deg_out + pins_src[e], 1.0f);
  atomicAdd(deg_in  + pins_dst[e], 1.0f);
  atomicAdd(deg_p   + pinned_dst[e], 1.0f);
  atomicAdd(deg_n   + near_dst[e], 1.0f);
}

// GraphConv message: agg[dst] += node_feat[src] * rsqrt(max(deg_out[src],1))
__global__ __launch_bounds__(256) void pins_edge_kernel(
    const float* __restrict__ node_feat, const int* __restrict__ src,
    const int* __restrict__ dst, const float* __restrict__ deg_out,
    float* __restrict__ agg) {
  int gid = blockIdx.x * 256 + threadIdx.x;
  int e = gid >> 5;
  if (e >= NE) return;
  int o = gid & 31;
  int s = src[e], d = dst[e];
  float ns = rsqrtf(fmaxf(deg_out[s], 1.0f));
  atomicAdd(agg + (size_t)d * 32 + o, node_feat[(size_t)s * 32 + o] * ns);
}

// NNConv direct-MFMA: per 16-edge tile, 17 MFMA steps (K=32 each).
// A[e, c*32+i] = pf[e,c] * feat[src_e, i]  (c=16 is the bias step, pf=1).
// Lane (er=lane&15, kg=lane>>4): A-frag = pf[er,c] * feat[s_er, kg*8..+8].
// pf[er,c] obtained by one __shfl from the lane that preloaded it.
// B-frags read linearly from LDS (lane-ordered layout, conflict-free).
// D (m89): col=lane&15=o', row=(lane>>4)*4+r=edge -> direct 4-edge x 16-col atomics.
__global__ __launch_bounds__(256) void nnconv_mfma_kernel(
    const float* __restrict__ feat0, const float* __restrict__ ef0,
    const int* __restrict__ src0, const int* __restrict__ dst0,
    const u16* __restrict__ WL0, float* __restrict__ acc0,
    const float* __restrict__ feat1, const float* __restrict__ ef1,
    const int* __restrict__ src1, const int* __restrict__ dst1,
    const u16* __restrict__ WL1, float* __restrict__ acc1,
    int nb0) {
  __shared__ u16 WS[WLN];
  bool rel = blockIdx.x >= nb0;
  int b = rel ? blockIdx.x - nb0 : blockIdx.x;
  const float* feat = rel ? feat1 : feat0;
  const float* ef   = rel ? ef1 : ef0;
  const int* srcp   = rel ? src1 : src0;
  const int* dstp   = rel ? dst1 : dst0;
  const u16* WLg    = rel ? WL1 : WL0;
  float* acc        = rel ? acc1 : acc0;

  for (int t = threadIdx.x; t < WLN / 8; t += 256)
    ((uint4*)WS)[t] = ((const uint4*)WLg)[t];
  __syncthreads();

  int w = threadIdx.x >> 6, lane = threadIdx.x & 63;
  int er = lane & 15, kg = lane >> 4;

  for (int it = 0; it < 4; ++it) {
    int tt = b * 16 + w * 4 + it;          // 16 tiles per block, 4 per wave
    if (tt >= 9375) break;                 // 150000/16 = 9375 exact tiles
    int e0 = tt * 16;
    int e = e0 + er;
    int s = srcp[e];
    const float* fp = feat + (size_t)s * 32 + kg * 8;
    float4 f0 = *(const float4*)fp;
    float4 f1 = *(const float4*)(fp + 4);
    float4 pq = *(const float4*)(ef + (size_t)e * 16 + kg * 4);  // pf[er, kg*4..+4]
    f32x4 a0 = {0.f, 0.f, 0.f, 0.f}, a1 = {0.f, 0.f, 0.f, 0.f};
#pragma unroll
    for (int c = 0; c < 16; ++c) {
      int srcl = er + 16 * (c >> 2);
      float pc = (c & 3) == 0 ? pq.x : (c & 3) == 1 ? pq.y : (c & 3) == 2 ? pq.z : pq.w;
      float pv = __shfl(pc, srcl, 64);     // = pf[e0+er, c]
      u32 d0, d1, d2, d3;
      asm("v_cvt_pk_bf16_f32 %0, %1, %2" : "=v"(d0) : "v"(pv * f0.x), "v"(pv * f0.y));
      asm("v_cvt_pk_bf16_f32 %0, %1, %2" : "=v"(d1) : "v"(pv * f0.z), "v"(pv * f0.w));
      asm("v_cvt_pk_bf16_f32 %0, %1, %2" : "=v"(d2) : "v"(pv * f1.x), "v"(pv * f1.y));
      asm("v_cvt_pk_bf16_f32 %0, %1, %2" : "=v"(d3) : "v"(pv * f1.z), "v"(pv * f1.w));
      short8v af;
      ((u32*)&af)[0] = d0; ((u32*)&af)[1] = d1; ((u32*)&af)[2] = d2; ((u32*)&af)[3] = d3;
      short8v b0 = *(const short8v*)(WS + (c * 2 + 0) * 512 + lane * 8);
      short8v b1 = *(const short8v*)(WS + (c * 2 + 1) * 512 + lane * 8);
      a0 = __builtin_amdgcn_mfma_f32_16x16x32_bf16(af, b0, a0, 0, 0, 0);
      a1 = __builtin_amdgcn_mfma_f32_16x16x32_bf16(af, b1, a1, 0, 0, 0);
    }
    {  // bias step c=16: A = feat (pf == 1)
      u32 d0, d1, d2, d3;
      asm("v_cvt_pk_bf16_f32 %0, %1, %2" : "=v"(d0) : "v"(f0.x), "v"(f0.y));
      asm("v_cvt_pk_bf16_f32 %0, %1, %2" : "=v"(d1) : "v"(f0.z), "v"(f0.w));
      asm("v_cvt_pk_bf16_f32 %0, %1, %2" : "=v"(d2) : "v"(f1.x), "v"(f1.y));
      asm("v_cvt_pk_bf16_f32 %0, %1, %2" : "=v"(d3) : "v"(f1.z), "v"(f1.w));
      short8v af;
      ((u32*)&af)[0] = d0; ((u32*)&af)[1] = d1; ((u32*)&af)[2] = d2; ((u32*)&af)[3] = d3;
      short8v b0 = *(const short8v*)(WS + 32 * 512 + lane * 8);
      short8v b1 = *(const short8v*)(WS + 33 * 512 + lane * 8);
      a0 = __builtin_amdgcn_mfma_f32_16x16x32_bf16(af, b0, a0, 0, 0, 0);
      a1 = __builtin_amdgcn_mfma_f32_16x16x32_bf16(af, b1, a1, 0, 0, 0);
    }
    // scatter: lane holds msg[edge kg*4+r][o'] in a0[r], msg[..][16+o'] in a1[r]
#pragma unroll
    for (int r = 0; r < 4; ++r) {
      int d = dstp[e0 + kg * 4 + r];
      float* ap = acc + (size_t)d * 32;
      atomicAdd(ap + er, a0[r]);        // er == o' here (both = lane&15)
      atomicAdd(ap + 16 + er, a1[r]);
    }
  }
}

// net_out = rsqrt(max(deg_in,1)) * (agg @ gc_w) + gc_b
__global__ __launch_bounds__(256) void net_out_kernel(
    const float* __restrict__ agg, const float* __restrict__ deg_in,
    const float* __restrict__ gc_w, const float* __restrict__ gc_b,
    float* __restrict__ out) {
  int gid = blockIdx.x * 256 + threadIdx.x;
  int m = gid >> 5;
  if (m >= N_NET) return;
  int o = gid & 31;
  float nd = rsqrtf(fmaxf(deg_in[m], 1.0f));
  const float* ag = agg + (size_t)m * 32;
  float a = 0.f;
#pragma unroll
  for (int j = 0; j < 32; ++j) a += ag[j] * gc_w[j * 32 + o];
  out[(size_t)N_NODE * 32 + (size_t)m * 32 + o] = a * nd + gc_b[o];
}

// node_out = max(acc_p/deg_p + pinned_b, acc_n/deg_n + near_b)
__global__ __launch_bounds__(256) void node_out_kernel(
    const float* __restrict__ acc_p, const float* __restrict__ acc_n,
    const float* __restrict__ deg_p, const float* __restrict__ deg_n,
    const float* __restrict__ pinned_b, const float* __restrict__ near_b,
    float* __restrict__ out) {
  int gid = blockIdx.x * 256 + threadIdx.x;
  int v = gid >> 5;
  if (v >= N_NODE) return;
  int o = gid & 31;
  float ap = acc_p[gid] / fmaxf(deg_p[v], 1.0f) + pinned_b[o];
  float an = acc_n[gid] / fmaxf(deg_n[v], 1.0f) + near_b[o];
  out[gid] = fmaxf(ap, an);
}

extern "C" void kernel_launch(void* const* d_in, const int* in_sizes, int n_in,
                              void* d_out, int out_size, void* d_ws, size_t ws_size,
                              hipStream_t stream) {
  const float* node_feat = (const float*)d_in[0];
  const float* net_feat  = (const float*)d_in[1];
  const float* pin_feat  = (const float*)d_in[2];
  const float* edge_feat = (const float*)d_in[3];
  const float* topo_w    = (const float*)d_in[4];
  const float* topo_b    = (const float*)d_in[5];
  const float* geom_w    = (const float*)d_in[6];
  const float* geom_b    = (const float*)d_in[7];
  const float* gc_w      = (const float*)d_in[8];
  const float* gc_b      = (const float*)d_in[9];
  const float* pinned_b  = (const float*)d_in[10];
  const float* near_b    = (const float*)d_in[11];
  const int* pins_src    = (const int*)d_in[12];
  const int* pins_dst    = (const int*)d_in[13];
  const int* pinned_src  = (const int*)d_in[14];
  const int* pinned_dst  = (const int*)d_in[15];
  const int* near_src    = (const int*)d_in[16];
  const int* near_dst    = (const int*)d_in[17];

  char* ws = (char*)d_ws;
  float* acc_p   = (float*)ws;            // 2,560,000 f32
  float* acc_n   = acc_p + 2560000;       // 2,560,000
  float* agg     = acc_n + 2560000;       //   640,000
  float* deg_out = agg + 640000;          //    80,000
  float* deg_in  = deg_out + 80000;       //    20,000
  float* deg_p   = deg_in + 20000;        //    80,000
  float* deg_n   = deg_p + 80000;         //    80,000
  size_t zero_bytes = (size_t)6020000 * 4;
  size_t off = (zero_bytes + 255) & ~(size_t)255;
  u16* WL0 = (u16*)(ws + off);  off += (size_t)WLN * 2;
  off = (off + 255) & ~(size_t)255;
  u16* WL1 = (u16*)(ws + off);

  hipMemsetAsync(d_ws, 0, zero_bytes, stream);
  wprep_kernel<<<136, 256, 0, stream>>>(topo_w, topo_b, geom_w, geom_b, WL0, WL1);
  deg_kernel<<<(NE + 255) / 256, 256, 0, stream>>>(pins_src, pins_dst, pinned_dst, near_dst,
                                                   deg_out, deg_in, deg_p, deg_n);
  pins_edge_kernel<<<NE * 32 / 256, 256, 0, stream>>>(node_feat, pins_src, pins_dst, deg_out, agg);
  int nb0 = 586;  // ceil(9375 tiles / 16 per block)
  nnconv_mfma_kernel<<<2 * nb0, 256, 0, stream>>>(
      net_feat,  pin_feat,  pinned_src, pinned_dst, WL0, acc_p,
      node_feat, edge_feat, near_src,   near_dst,   WL1, acc_n, nb0);
  net_out_kernel<<<N_NET * 32 / 256, 256, 0, stream>>>(agg, deg_in, gc_w, gc_b, (float*)d_out);
  node_out_kernel<<<N_NODE * 32 / 256, 256, 0, stream>>>(acc_p, acc_n, deg_p, deg_n,
                                                         pinned_b, near_b, (float*)d_out);
}

// Round 5
// 211.005 us; speedup vs baseline: 3.5604x; 1.0088x over previous
//
#include <hip/hip_runtime.h>

#define N_NODE 80000
#define N_NET  20000
#define NE     150000
#define WLN    17408   // 34 c2h-steps * 512 u16 (64 lanes * 8 bf16) per relation

typedef unsigned short u16;
typedef unsigned int u32;
typedef __attribute__((ext_vector_type(8))) short short8v;
typedef __attribute__((ext_vector_type(4))) float f32x4;

static __device__ __forceinline__ u16 f2bf(float f) {
  u32 x = __float_as_uint(f);
  x += 0x7fffu + ((x >> 16) & 1u);   // round-to-nearest-even
  return (u16)(x >> 16);
}

// Build W' tables in exact MFMA B-fragment lane order, per relation:
//   K-index = k*32 + i (k-major).  Step c (0..16), half h (o = 16h+o'):
//   WL[(c*2+h)*512 + lane*8 + j] = W'[(c, kg*8+j), 16h+o']   (lane = kg*16+o')
//   W'[(k,i),o] = W[(i*32+o)*16 + k] for k<16;  = b[i*32+o] for k==16 (bias).
__global__ __launch_bounds__(256) void wprep_kernel(
    const float* __restrict__ topo_w, const float* __restrict__ topo_b,
    const float* __restrict__ geom_w, const float* __restrict__ geom_b,
    u16* __restrict__ WL0, u16* __restrict__ WL1) {
  int idx = blockIdx.x * 256 + threadIdx.x;   // 2*17408 = 34816 exact
  int rel = idx / WLN;
  int g = idx % WLN;
  int c2h = g >> 9, l = (g >> 3) & 63, j = g & 7;
  int op = l & 15, kg = l >> 4, c = c2h >> 1, h = c2h & 1;
  int i = kg * 8 + j, o = 16 * h + op;
  const float* w = rel ? geom_w : topo_w;
  const float* b = rel ? geom_b : topo_b;
  float v = (c < 16) ? w[(i * 32 + o) * 16 + c] : b[i * 32 + o];
  (rel ? WL1 : WL0)[g] = f2bf(v);
}

__global__ __launch_bounds__(256) void deg_kernel(
    const int* __restrict__ pins_src, const int* __restrict__ pins_dst,
    const int* __restrict__ pinned_dst, const int* __restrict__ near_dst,
    float* __restrict__ deg_out, float* __restrict__ deg_in,
    float* __restrict__ deg_p, float* __restrict__ deg_n) {
  int e = blockIdx.x * 256 + threadIdx.x;
  if (e >= NE) return;
  atomicAdd(deg_out + pins_src[e], 1.0f);
  atomicAdd(deg_in  + pins_dst[e], 1.0f);
  atomicAdd(deg_p   + pinned_dst[e], 1.0f);
  atomicAdd(deg_n   + near_dst[e], 1.0f);
}

// GraphConv message: agg[dst] += node_feat[src] * rsqrt(max(deg_out[src],1))
__global__ __launch_bounds__(256) void pins_edge_kernel(
    const float* __restrict__ node_feat, const int* __restrict__ src,
    const int* __restrict__ dst, const float* __restrict__ deg_out,
    float* __restrict__ agg) {
  int gid = blockIdx.x * 256 + threadIdx.x;
  int e = gid >> 5;
  if (e >= NE) return;
  int o = gid & 31;
  int s = src[e], d = dst[e];
  float ns = rsqrtf(fmaxf(deg_out[s], 1.0f));
  atomicAdd(agg + (size_t)d * 32 + o, node_feat[(size_t)s * 32 + o] * ns);
}

// NNConv direct-MFMA: per 16-edge tile, 17 MFMA steps (K=32 each).
// A[e, c*32+i] = pf[e,c] * feat[src_e, i]  (c=16 is the bias step, pf=1).
// Lane (er=lane&15, kg=lane>>4): A-frag = pf[er,c] * feat[s_er, kg*8..+8].
// pf[er,c] obtained by one __shfl from the lane that preloaded it.
// B-frags read linearly from LDS (lane-ordered layout, conflict-free).
// D (m89): col=lane&15=o', row=(lane>>4)*4+r=edge -> direct 4-edge x 16-col atomics.
// 512-thread blocks: 8 waves share one 34KB WS copy -> 4 blocks/CU = 32 waves/CU
// (256-thread blocks capped residency at 16 waves/CU via LDS; occupancy was 27%).
__global__ __launch_bounds__(512) void nnconv_mfma_kernel(
    const float* __restrict__ feat0, const float* __restrict__ ef0,
    const int* __restrict__ src0, const int* __restrict__ dst0,
    const u16* __restrict__ WL0, float* __restrict__ acc0,
    const float* __restrict__ feat1, const float* __restrict__ ef1,
    const int* __restrict__ src1, const int* __restrict__ dst1,
    const u16* __restrict__ WL1, float* __restrict__ acc1,
    int nb0) {
  __shared__ u16 WS[WLN];
  bool rel = blockIdx.x >= nb0;
  int b = rel ? blockIdx.x - nb0 : blockIdx.x;
  const float* feat = rel ? feat1 : feat0;
  const float* ef   = rel ? ef1 : ef0;
  const int* srcp   = rel ? src1 : src0;
  const int* dstp   = rel ? dst1 : dst0;
  const u16* WLg    = rel ? WL1 : WL0;
  float* acc        = rel ? acc1 : acc0;

  for (int t = threadIdx.x; t < WLN / 8; t += 512)
    ((uint4*)WS)[t] = ((const uint4*)WLg)[t];
  __syncthreads();

  int w = threadIdx.x >> 6, lane = threadIdx.x & 63;
  int er = lane & 15, kg = lane >> 4;

#pragma unroll
  for (int it = 0; it < 2; ++it) {
    int tt = b * 16 + w * 2 + it;          // 16 tiles per block, 2 per wave
    if (tt >= 9375) continue;              // 150000/16 = 9375 exact tiles
    int e0 = tt * 16;
    int e = e0 + er;
    int s = srcp[e];
    const float* fp = feat + (size_t)s * 32 + kg * 8;
    float4 f0 = *(const float4*)fp;
    float4 f1 = *(const float4*)(fp + 4);
    float4 pq = *(const float4*)(ef + (size_t)e * 16 + kg * 4);  // pf[er, kg*4..+4]
    f32x4 a0 = {0.f, 0.f, 0.f, 0.f}, a1 = {0.f, 0.f, 0.f, 0.f};
#pragma unroll
    for (int c = 0; c < 16; ++c) {
      int srcl = er + 16 * (c >> 2);
      float pc = (c & 3) == 0 ? pq.x : (c & 3) == 1 ? pq.y : (c & 3) == 2 ? pq.z : pq.w;
      float pv = __shfl(pc, srcl, 64);     // = pf[e0+er, c]
      u32 d0, d1, d2, d3;
      asm("v_cvt_pk_bf16_f32 %0, %1, %2" : "=v"(d0) : "v"(pv * f0.x), "v"(pv * f0.y));
      asm("v_cvt_pk_bf16_f32 %0, %1, %2" : "=v"(d1) : "v"(pv * f0.z), "v"(pv * f0.w));
      asm("v_cvt_pk_bf16_f32 %0, %1, %2" : "=v"(d2) : "v"(pv * f1.x), "v"(pv * f1.y));
      asm("v_cvt_pk_bf16_f32 %0, %1, %2" : "=v"(d3) : "v"(pv * f1.z), "v"(pv * f1.w));
      short8v af;
      ((u32*)&af)[0] = d0; ((u32*)&af)[1] = d1; ((u32*)&af)[2] = d2; ((u32*)&af)[3] = d3;
      short8v b0 = *(const short8v*)(WS + (c * 2 + 0) * 512 + lane * 8);
      short8v b1 = *(const short8v*)(WS + (c * 2 + 1) * 512 + lane * 8);
      a0 = __builtin_amdgcn_mfma_f32_16x16x32_bf16(af, b0, a0, 0, 0, 0);
      a1 = __builtin_amdgcn_mfma_f32_16x16x32_bf16(af, b1, a1, 0, 0, 0);
    }
    {  // bias step c=16: A = feat (pf == 1)
      u32 d0, d1, d2, d3;
      asm("v_cvt_pk_bf16_f32 %0, %1, %2" : "=v"(d0) : "v"(f0.x), "v"(f0.y));
      asm("v_cvt_pk_bf16_f32 %0, %1, %2" : "=v"(d1) : "v"(f0.z), "v"(f0.w));
      asm("v_cvt_pk_bf16_f32 %0, %1, %2" : "=v"(d2) : "v"(f1.x), "v"(f1.y));
      asm("v_cvt_pk_bf16_f32 %0, %1, %2" : "=v"(d3) : "v"(f1.z), "v"(f1.w));
      short8v af;
      ((u32*)&af)[0] = d0; ((u32*)&af)[1] = d1; ((u32*)&af)[2] = d2; ((u32*)&af)[3] = d3;
      short8v b0 = *(const short8v*)(WS + 32 * 512 + lane * 8);
      short8v b1 = *(const short8v*)(WS + 33 * 512 + lane * 8);
      a0 = __builtin_amdgcn_mfma_f32_16x16x32_bf16(af, b0, a0, 0, 0, 0);
      a1 = __builtin_amdgcn_mfma_f32_16x16x32_bf16(af, b1, a1, 0, 0, 0);
    }
    // scatter: lane holds msg[edge kg*4+r][o'] in a0[r], msg[..][16+o'] in a1[r]
#pragma unroll
    for (int r = 0; r < 4; ++r) {
      int d = dstp[e0 + kg * 4 + r];
      float* ap = acc + (size_t)d * 32;
      atomicAdd(ap + er, a0[r]);        // er == o' here (both = lane&15)
      atomicAdd(ap + 16 + er, a1[r]);
    }
  }
}

// net_out = rsqrt(max(deg_in,1)) * (agg @ gc_w) + gc_b
__global__ __launch_bounds__(256) void net_out_kernel(
    const float* __restrict__ agg, const float* __restrict__ deg_in,
    const float* __restrict__ gc_w, const float* __restrict__ gc_b,
    float* __restrict__ out) {
  int gid = blockIdx.x * 256 + threadIdx.x;
  int m = gid >> 5;
  if (m >= N_NET) return;
  int o = gid & 31;
  float nd = rsqrtf(fmaxf(deg_in[m], 1.0f));
  const float* ag = agg + (size_t)m * 32;
  float a = 0.f;
#pragma unroll
  for (int j = 0; j < 32; ++j) a += ag[j] * gc_w[j * 32 + o];
  out[(size_t)N_NODE * 32 + (size_t)m * 32 + o] = a * nd + gc_b[o];
}

// node_out = max(acc_p/deg_p + pinned_b, acc_n/deg_n + near_b)
__global__ __launch_bounds__(256) void node_out_kernel(
    const float* __restrict__ acc_p, const float* __restrict__ acc_n,
    const float* __restrict__ deg_p, const float* __restrict__ deg_n,
    const float* __restrict__ pinned_b, const float* __restrict__ near_b,
    float* __restrict__ out) {
  int gid = blockIdx.x * 256 + threadIdx.x;
  int v = gid >> 5;
  if (v >= N_NODE) return;
  int o = gid & 31;
  float ap = acc_p[gid] / fmaxf(deg_p[v], 1.0f) + pinned_b[o];
  float an = acc_n[gid] / fmaxf(deg_n[v], 1.0f) + near_b[o];
  out[gid] = fmaxf(ap, an);
}

extern "C" void kernel_launch(void* const* d_in, const int* in_sizes, int n_in,
                              void* d_out, int out_size, void* d_ws, size_t ws_size,
                              hipStream_t stream) {
  const float* node_feat = (const float*)d_in[0];
  const float* net_feat  = (const float*)d_in[1];
  const float* pin_feat  = (const float*)d_in[2];
  const float* edge_feat = (const float*)d_in[3];
  const float* topo_w    = (const float*)d_in[4];
  const float* topo_b    = (const float*)d_in[5];
  const float* geom_w    = (const float*)d_in[6];
  const float* geom_b    = (const float*)d_in[7];
  const float* gc_w      = (const float*)d_in[8];
  const float* gc_b      = (const float*)d_in[9];
  const float* pinned_b  = (const float*)d_in[10];
  const float* near_b    = (const float*)d_in[11];
  const int* pins_src    = (const int*)d_in[12];
  const int* pins_dst    = (const int*)d_in[13];
  const int* pinned_src  = (const int*)d_in[14];
  const int* pinned_dst  = (const int*)d_in[15];
  const int* near_src    = (const int*)d_in[16];
  const int* near_dst    = (const int*)d_in[17];

  char* ws = (char*)d_ws;
  float* acc_p   = (float*)ws;            // 2,560,000 f32
  float* acc_n   = acc_p + 2560000;       // 2,560,000
  float* agg     = acc_n + 2560000;       //   640,000
  float* deg_out = agg + 640000;          //    80,000
  float* deg_in  = deg_out + 80000;       //    20,000
  float* deg_p   = deg_in + 20000;        //    80,000
  float* deg_n   = deg_p + 80000;         //    80,000
  size_t zero_bytes = (size_t)6020000 * 4;
  size_t off = (zero_bytes + 255) & ~(size_t)255;
  u16* WL0 = (u16*)(ws + off);  off += (size_t)WLN * 2;
  off = (off + 255) & ~(size_t)255;
  u16* WL1 = (u16*)(ws + off);

  hipMemsetAsync(d_ws, 0, zero_bytes, stream);
  wprep_kernel<<<136, 256, 0, stream>>>(topo_w, topo_b, geom_w, geom_b, WL0, WL1);
  deg_kernel<<<(NE + 255) / 256, 256, 0, stream>>>(pins_src, pins_dst, pinned_dst, near_dst,
                                                   deg_out, deg_in, deg_p, deg_n);
  pins_edge_kernel<<<NE * 32 / 256, 256, 0, stream>>>(node_feat, pins_src, pins_dst, deg_out, agg);
  int nb0 = 586;  // ceil(9375 tiles / 16 per block), 8 waves x 2 tiles each
  nnconv_mfma_kernel<<<2 * nb0, 512, 0, stream>>>(
      net_feat,  pin_feat,  pinned_src, pinned_dst, WL0, acc_p,
      node_feat, edge_feat, near_src,   near_dst,   WL1, acc_n, nb0);
  net_out_kernel<<<N_NET * 32 / 256, 256, 0, stream>>>(agg, deg_in, gc_w, gc_b, (float*)d_out);
  node_out_kernel<<<N_NODE * 32 / 256, 256, 0, stream>>>(acc_p, acc_n, deg_p, deg_n,
                                                         pinned_b, near_b, (float*)d_out);
}